// Round 4
// baseline (302.645 us; speedup 1.0000x reference)
//
#include <hip/hip_runtime.h>
#include <hip/hip_bf16.h>
#include <stdint.h>
#include <stddef.h>

typedef __bf16 bf16_t;
typedef __bf16 bf16x8 __attribute__((ext_vector_type(8)));
typedef __bf16 bf16x4 __attribute__((ext_vector_type(4)));
typedef float  f32x4  __attribute__((ext_vector_type(4)));

#define T_SEQ 2032
#define T_PAD 2048
#define DM    1408
#define NHEAD 16
#define HD    88
#define HP    96
#define KVB   128
#define NT    (T_PAD / KVB)
#define SM_SCALE 0.10660035817780521f   // 88^-0.5
#define LOG2E 1.4426950408889634f
#define DEFER_THR 8.0f

// -------- async global->LDS (16B per lane, wave-uniform LDS base) --------
__device__ __forceinline__ void gload_lds16(const bf16_t* g, bf16_t* l) {
  __builtin_amdgcn_global_load_lds(
      (__attribute__((address_space(1))) void*)(g),
      (__attribute__((address_space(3))) void*)(l), 16, 0, 0);
}

// ---------------- convert x (f32 [2032][1408]) -> bf16 [2048][1408], pad 0
__global__ void k_convert_x(const float* __restrict__ x, bf16_t* __restrict__ Xb) {
  int idx = blockIdx.x * 256 + threadIdx.x;
  const int total = T_PAD * DM / 4;
  if (idx >= total) return;
  int base = idx * 4;
  int t = base / DM;
  float4 v;
  if (t < T_SEQ) v = *(const float4*)(x + base);
  else           v = make_float4(0.f, 0.f, 0.f, 0.f);
  bf16x4 o;
  o[0] = (bf16_t)v.x; o[1] = (bf16_t)v.y; o[2] = (bf16_t)v.z; o[3] = (bf16_t)v.w;
  *(bf16x4*)(Xb + base) = o;
}

// ---------------- transpose+convert, 64x64 tiles, vectorized both sides
// grid = nw * 484; which<3 -> d012 + which*DM*DM, which==3 -> d3
__global__ void k_transpose4(const float* __restrict__ W0, const float* __restrict__ W1,
                             const float* __restrict__ W2, const float* __restrict__ W3,
                             bf16_t* __restrict__ d012, bf16_t* __restrict__ d3) {
  const int which = blockIdx.x / 484;
  const int b = blockIdx.x % 484;
  const float* src = (which == 0) ? W0 : (which == 1) ? W1 : (which == 2) ? W2 : W3;
  bf16_t* dst = (which < 3) ? (d012 + (size_t)which * DM * DM) : d3;
  const int tr = b / 22, tc = b % 22;
  __shared__ float tile[64][65];
  const int t = threadIdx.x;
  const int row = t >> 2, l4 = t & 3;
#pragma unroll
  for (int i = 0; i < 4; ++i) {
    float4 v = *(const float4*)(src + (size_t)(tr * 64 + row) * DM + tc * 64 + l4 * 16 + i * 4);
    *(float4*)&tile[row][l4 * 16 + i * 4] = v;
  }
  __syncthreads();
  const int jj = t >> 2;
#pragma unroll
  for (int it = 0; it < 2; ++it) {
    const int c = (t & 3) + 4 * it;
    bf16x8 o;
#pragma unroll
    for (int e = 0; e < 8; ++e) o[e] = (bf16_t)tile[c * 8 + e][jj];
    *(bf16x8*)(dst + (size_t)(tc * 64 + jj) * DM + tr * 64 + c * 8) = o;
  }
}

// ---------------- shared GEMM mainloop: 128x128 tile, BK=32, double-buffered
__device__ __forceinline__ void gemm_main_1408(
    const bf16_t* __restrict__ A, const bf16_t* __restrict__ Bt,
    bf16_t* As, bf16_t* Bs,   // each 2 bufs x 4096 elems
    int m0, int n0, f32x4 acc[4][4]) {
  const int tid = threadIdx.x;
  const int w = tid >> 6, lane = tid & 63;
  const int l15 = lane & 15, lg = lane >> 4;
  const int b0 = w * 2048 + lane * 16;
  const int r0 = b0 >> 6, k0 = (b0 & 63) >> 1;
  const int b1 = b0 + 1024;
  const int r1 = b1 >> 6, k1 = (b1 & 63) >> 1;
  const int wr = w >> 1, wc = w & 1;
  const size_t aoff0 = (size_t)(m0 + r0) * DM + k0;
  const size_t aoff1 = (size_t)(m0 + r1) * DM + k1;
  const size_t boff0 = (size_t)(n0 + r0) * DM + k0;
  const size_t boff1 = (size_t)(n0 + r1) * DM + k1;
  // prologue: tile 0 -> buf 0
  gload_lds16(A + aoff0, As + w * 1024);
  gload_lds16(A + aoff1, As + w * 1024 + 512);
  gload_lds16(Bt + boff0, Bs + w * 1024);
  gload_lds16(Bt + boff1, Bs + w * 1024 + 512);
  for (int kt = 0; kt < 44; ++kt) {
    const int cur = kt & 1;
    const int kon = ((kt < 43) ? kt + 1 : 43) * 32;   // clamp: dummy refetch last
    const int db = (cur ^ 1) * 4096;
    gload_lds16(A + aoff0 + kon, As + db + w * 1024);
    gload_lds16(A + aoff1 + kon, As + db + w * 1024 + 512);
    gload_lds16(Bt + boff0 + kon, Bs + db + w * 1024);
    gload_lds16(Bt + boff1 + kon, Bs + db + w * 1024 + 512);
    asm volatile("s_waitcnt vmcnt(4)" ::: "memory");
    __builtin_amdgcn_s_barrier();
    const bf16_t* Ac = As + cur * 4096;
    const bf16_t* Bc = Bs + cur * 4096;
    bf16x8 av[4], bv[4];
#pragma unroll
    for (int m = 0; m < 4; ++m)
      av[m] = *(const bf16x8*)(Ac + (wr * 64 + m * 16 + l15) * 32 + lg * 8);
#pragma unroll
    for (int n = 0; n < 4; ++n)
      bv[n] = *(const bf16x8*)(Bc + (wc * 64 + n * 16 + l15) * 32 + lg * 8);
    __builtin_amdgcn_s_setprio(1);
#pragma unroll
    for (int m = 0; m < 4; ++m)
#pragma unroll
      for (int n = 0; n < 4; ++n)
        acc[m][n] = __builtin_amdgcn_mfma_f32_16x16x32_bf16(av[m], bv[n], acc[m][n], 0, 0, 0);
    __builtin_amdgcn_s_setprio(0);
    __builtin_amdgcn_s_barrier();
  }
  asm volatile("s_waitcnt vmcnt(0)" ::: "memory");
}

// ---------------- GEMM 1: X @ Wqkv^T -> Q/K/V scatter, fused RoPE + bias
__global__ __launch_bounds__(256, 2) void k_gemm_qkv(
    const bf16_t* __restrict__ A, const bf16_t* __restrict__ Bt,
    const float* __restrict__ bq, const float* __restrict__ bk,
    const float* __restrict__ bvp, const float* __restrict__ freqs,
    bf16_t* __restrict__ Qh, bf16_t* __restrict__ Kh, bf16_t* __restrict__ Vt) {
  __shared__ bf16_t As[2 * 4096];
  __shared__ bf16_t Bs[2 * 4096];
  const int bid = blockIdx.x;
  const int sbid = (bid & 7) * 66 + (bid >> 3);   // XCD swizzle (528 = 66*8)
  const int mt = sbid / 33, nt = sbid % 33;
  f32x4 acc[4][4];
#pragma unroll
  for (int m = 0; m < 4; ++m)
#pragma unroll
    for (int n = 0; n < 4; ++n) acc[m][n] = (f32x4){0.f, 0.f, 0.f, 0.f};
  gemm_main_1408(A, Bt, As, Bs, mt * 128, nt * 128, acc);
  const int tid = threadIdx.x, w = tid >> 6, lane = tid & 63;
  const int l15 = lane & 15, lg = lane >> 4;
  const int wr = w >> 1, wc = w & 1;
  const int cb = nt * 128 + wc * 64, rb = mt * 128 + wr * 64;
#pragma unroll
  for (int n = 0; n < 4; ++n) {
    const int col = cb + n * 16 + l15;
    const int seg = (col >= 2 * DM) ? 2 : ((col >= DM) ? 1 : 0);
    const int cc = col - seg * DM;
    const float* bp = (seg == 0) ? bq : (seg == 1) ? bk : bvp;
    const float bval = bp[cc];
    const int hn = cc / 88;
    const int hh = cc - hn * 88;
    const int hbase = hh & ~1;
    const bool odd = hh & 1;
#pragma unroll
    for (int m = 0; m < 4; ++m) {
      const int tb = rb + m * 16 + lg * 4;
      if (seg == 2) {
        bf16x4 vv;
#pragma unroll
        for (int r = 0; r < 4; ++r) vv[r] = (bf16_t)(acc[m][n][r] + bval);
        *(bf16x4*)(Vt + ((size_t)hn * HP + hh) * T_PAD + tb) = vv;
      } else {
#pragma unroll
        for (int r = 0; r < 4; ++r) {
          const int t = tb + r;
          const float v = acc[m][n][r] + bval;
          const float p = __shfl_xor(v, 1);     // partner column (hh^1)
          const int tc2 = (t < T_SEQ) ? t : 0;
          const float c = freqs[tc2 * 88 + hbase];
          const float s = freqs[tc2 * 88 + hbase + 1];
          const float x1 = odd ? p : v;
          const float x2 = odd ? v : p;
          const float ro = odd ? (x1 * s + x2 * c) : (x1 * c - x2 * s);
          if (seg == 0)
            Qh[((size_t)hn * T_PAD + t) * HP + hh] = (bf16_t)(ro * (SM_SCALE * LOG2E));
          else
            Kh[((size_t)hn * T_PAD + t) * HP + hh] = (bf16_t)ro;
        }
      }
    }
  }
}

// ---------------- GEMM 2: attnout @ Wo^T + bo -> f32 out, BM=64, dbuf
__global__ __launch_bounds__(256, 2) void k_gemm_out64(
    const bf16_t* __restrict__ A, const bf16_t* __restrict__ Bt,
    const float* __restrict__ bo, float* __restrict__ out) {
  __shared__ bf16_t Sm[2 * 6144];   // per buf: A[64][32] @0, B[128][32] @2048
  const int bid = blockIdx.x;
  const int sbid = (bid & 7) * 44 + (bid >> 3);   // XCD swizzle (352 = 44*8)
  const int mt = sbid / 11, nt = sbid % 11;
  const int m0 = mt * 64, n0 = nt * 128;
  const int tid = threadIdx.x, w = tid >> 6, lane = tid & 63;
  const int l15 = lane & 15, lg = lane >> 4;
  const bf16_t* srcp[3];
  size_t srco[3];
  int dste[3];
#pragma unroll
  for (int p = 0; p < 3; ++p) {
    const int off = w * 3072 + p * 1024;
    const int o = off + lane * 16;
    dste[p] = off >> 1;
    if (off < 4096) {
      int r = o >> 6, k = (o & 63) >> 1;
      srcp[p] = A; srco[p] = (size_t)(m0 + r) * DM + k;
    } else {
      int ob = o - 4096;
      int r = ob >> 6, k = (ob & 63) >> 1;
      srcp[p] = Bt; srco[p] = (size_t)(n0 + r) * DM + k;
    }
  }
  f32x4 acc[4][2];
#pragma unroll
  for (int m = 0; m < 4; ++m)
#pragma unroll
    for (int n = 0; n < 2; ++n) acc[m][n] = (f32x4){0.f, 0.f, 0.f, 0.f};
  // prologue tile 0 -> buf 0
#pragma unroll
  for (int p = 0; p < 3; ++p) gload_lds16(srcp[p] + srco[p], Sm + dste[p]);
  for (int kt = 0; kt < 44; ++kt) {
    const int cur = kt & 1;
    const int kon = ((kt < 43) ? kt + 1 : 43) * 32;
    const int db = (cur ^ 1) * 6144;
#pragma unroll
    for (int p = 0; p < 3; ++p)
      gload_lds16(srcp[p] + srco[p] + kon, Sm + db + dste[p]);
    asm volatile("s_waitcnt vmcnt(3)" ::: "memory");
    __builtin_amdgcn_s_barrier();
    const bf16_t* Sc = Sm + cur * 6144;
    bf16x8 av[4], bv2[2];
#pragma unroll
    for (int m = 0; m < 4; ++m)
      av[m] = *(const bf16x8*)(Sc + (m * 16 + l15) * 32 + lg * 8);
#pragma unroll
    for (int n = 0; n < 2; ++n)
      bv2[n] = *(const bf16x8*)(Sc + 2048 + (w * 32 + n * 16 + l15) * 32 + lg * 8);
    __builtin_amdgcn_s_setprio(1);
#pragma unroll
    for (int m = 0; m < 4; ++m)
#pragma unroll
      for (int n = 0; n < 2; ++n)
        acc[m][n] = __builtin_amdgcn_mfma_f32_16x16x32_bf16(av[m], bv2[n], acc[m][n], 0, 0, 0);
    __builtin_amdgcn_s_setprio(0);
    __builtin_amdgcn_s_barrier();
  }
  asm volatile("s_waitcnt vmcnt(0)" ::: "memory");
  const int cb = n0 + w * 32;
#pragma unroll
  for (int n = 0; n < 2; ++n) {
    const int col = cb + n * 16 + l15;
    const float bval = bo[col];
#pragma unroll
    for (int m = 0; m < 4; ++m) {
#pragma unroll
      for (int r = 0; r < 4; ++r) {
        const int t = m0 + m * 16 + lg * 4 + r;
        if (t < T_SEQ) out[(size_t)t * DM + col] = acc[m][n][r] + bval;
      }
    }
  }
}

// ---------------- flash attention: barrier-free, K/V direct from L2
// 1 WG = (head, 64 q rows), 4 waves x 16 rows, KVB=128, swapped QK^T,
// exp2 domain (log2e folded into Q), defer-max (THR=8), per-wave P bounce.
__global__ __launch_bounds__(256, 2) void k_attn(
    const bf16_t* __restrict__ Qh, const bf16_t* __restrict__ Kh,
    const bf16_t* __restrict__ Vt, bf16_t* __restrict__ Ob) {
  __shared__ bf16_t Ps[4][16 * 136];   // per-wave P[q][k], stride 136 (2-way free)
  const int tid = threadIdx.x;
  const int w = tid >> 6, lane = tid & 63;
  const int l15 = lane & 15, lg = lane >> 4;
  const int bid = blockIdx.x;
  const int sbid = (bid & 7) * 64 + (bid >> 3);   // XCD swizzle (512 = 64*8)
  const int head = sbid >> 5;
  const int qt = sbid & 31;
  const bf16_t* Qn = Qh + (size_t)head * T_PAD * HP;
  const bf16_t* Kn = Kh + (size_t)head * T_PAD * HP;
  const bf16_t* Vn = Vt + (size_t)head * HP * T_PAD;
  const int q0 = qt * 64 + w * 16;

  bf16x8 qf[3];
#pragma unroll
  for (int kh = 0; kh < 3; ++kh)
    qf[kh] = *(const bf16x8*)(Qn + (size_t)(q0 + l15) * HP + kh * 32 + lg * 8);

  f32x4 oacc[6];
#pragma unroll
  for (int j = 0; j < 6; ++j) oacc[j] = (f32x4){0.f, 0.f, 0.f, 0.f};
  float mrow = -1e30f;   // per-lane: q = l15 (log2 domain)
  float lrowp = 0.f;     // per-lane partial sum for q = l15

  for (int kvt = 0; kvt < NT; ++kvt) {
    const int s0 = kvt * KVB;
    f32x4 sf[8];
    // S^T = K @ Q^T in two half-tiles (keeps kf at 12 regs live)
#pragma unroll
    for (int half = 0; half < 2; ++half) {
      bf16x8 kf[12];
#pragma unroll
      for (int ss = 0; ss < 4; ++ss)
#pragma unroll
        for (int kh = 0; kh < 3; ++kh)
          kf[ss * 3 + kh] = *(const bf16x8*)(
              Kn + (size_t)(s0 + (half * 4 + ss) * 16 + l15) * HP + kh * 32 + lg * 8);
      __builtin_amdgcn_s_setprio(1);
#pragma unroll
      for (int ss = 0; ss < 4; ++ss) {
        f32x4 s = {0.f, 0.f, 0.f, 0.f};
#pragma unroll
        for (int kh = 0; kh < 3; ++kh)
          s = __builtin_amdgcn_mfma_f32_16x16x32_bf16(kf[ss * 3 + kh], qf[kh], s, 0, 0, 0);
        sf[half * 4 + ss] = s;
      }
      __builtin_amdgcn_s_setprio(0);
    }
    // prefetch V for ks=0,1 (consumed after softmax)
    bf16x8 vfA[12];
#pragma unroll
    for (int ks = 0; ks < 2; ++ks)
#pragma unroll
      for (int j = 0; j < 6; ++j)
        vfA[ks * 6 + j] = *(const bf16x8*)(
            Vn + (size_t)(j * 16 + l15) * T_PAD + s0 + ks * 32 + lg * 8);
    // mask rows >= T_SEQ (k index = s0 + ss*16 + lg*4 + r), last tile only
    if (s0 + KVB > T_SEQ) {
#pragma unroll
      for (int ss = 0; ss < 8; ++ss)
#pragma unroll
        for (int r = 0; r < 4; ++r)
          if (s0 + ss * 16 + lg * 4 + r >= T_SEQ) sf[ss][r] = -1e30f;
    }
    // row max: in-register tree + 2 shfl (k spread over lg groups)
    float tm = sf[0][0];
#pragma unroll
    for (int ss = 0; ss < 8; ++ss)
#pragma unroll
      for (int r = 0; r < 4; ++r) tm = fmaxf(tm, sf[ss][r]);
    tm = fmaxf(tm, __shfl_xor(tm, 16));
    tm = fmaxf(tm, __shfl_xor(tm, 32));
    // defer-max: rescale only when max grows beyond THR (wave-uniform branch)
    if (!__all(tm <= mrow + DEFER_THR)) {
      const float mn = fmaxf(mrow, tm);
      const float scv = __builtin_amdgcn_exp2f(mrow - mn);
      mrow = mn;
      lrowp *= scv;
#pragma unroll
      for (int r = 0; r < 4; ++r) {
        const float sq = __shfl(scv, lg * 4 + r, 16);
#pragma unroll
        for (int j = 0; j < 6; ++j) oacc[j][r] *= sq;
      }
    }
    // P = exp2(S - m), per-lane partial sum, store to per-wave LDS
    float rs = 0.f;
#pragma unroll
    for (int ss = 0; ss < 8; ++ss)
#pragma unroll
      for (int r = 0; r < 4; ++r) {
        const float p = __builtin_amdgcn_exp2f(sf[ss][r] - mrow);
        rs += p;
        Ps[w][l15 * 136 + ss * 16 + lg * 4 + r] = (bf16_t)p;
      }
    lrowp += rs;
    // prefetch V for ks=2,3
    bf16x8 vfB[12];
#pragma unroll
    for (int ks = 0; ks < 2; ++ks)
#pragma unroll
      for (int j = 0; j < 6; ++j)
        vfB[ks * 6 + j] = *(const bf16x8*)(
            Vn + (size_t)(j * 16 + l15) * T_PAD + s0 + (ks + 2) * 32 + lg * 8);
    // O += P @ V
    __builtin_amdgcn_s_setprio(1);
#pragma unroll
    for (int ks = 0; ks < 2; ++ks) {
      bf16x8 pa = *(const bf16x8*)(&Ps[w][l15 * 136 + ks * 32 + lg * 8]);
#pragma unroll
      for (int j = 0; j < 6; ++j)
        oacc[j] = __builtin_amdgcn_mfma_f32_16x16x32_bf16(pa, vfA[ks * 6 + j], oacc[j], 0, 0, 0);
    }
#pragma unroll
    for (int ks = 0; ks < 2; ++ks) {
      bf16x8 pa = *(const bf16x8*)(&Ps[w][l15 * 136 + (ks + 2) * 32 + lg * 8]);
#pragma unroll
      for (int j = 0; j < 6; ++j)
        oacc[j] = __builtin_amdgcn_mfma_f32_16x16x32_bf16(pa, vfB[ks * 6 + j], oacc[j], 0, 0, 0);
    }
    __builtin_amdgcn_s_setprio(0);
  }
  // final row-sum: finish cross-lg reduce, then fetch per-oacc-row value
  lrowp += __shfl_xor(lrowp, 16);
  lrowp += __shfl_xor(lrowp, 32);
  float lq[4];
#pragma unroll
  for (int r = 0; r < 4; ++r) lq[r] = __shfl(lrowp, lg * 4 + r, 16);
  // write attention output, [t][n*88+h] bf16
#pragma unroll
  for (int j = 0; j < 6; ++j) {
    const int h = j * 16 + l15;
    if (h < HD) {
#pragma unroll
      for (int r = 0; r < 4; ++r) {
        const int t = q0 + lg * 4 + r;
        if (t < T_SEQ)
          Ob[(size_t)t * DM + head * HD + h] = (bf16_t)(oacc[j][r] / lq[r]);
      }
    }
  }
}

// ---------------- host side ----------------
extern "C" void kernel_launch(void* const* d_in, const int* in_sizes, int n_in,
                              void* d_out, int out_size, void* d_ws, size_t ws_size,
                              hipStream_t stream) {
  (void)in_sizes; (void)n_in; (void)out_size;
  const float* x     = (const float*)d_in[0];
  const float* freqs = (const float*)d_in[1];
  const float* Wq    = (const float*)d_in[2];
  const float* bq    = (const float*)d_in[3];
  const float* Wk    = (const float*)d_in[4];
  const float* bk    = (const float*)d_in[5];
  const float* Wv    = (const float*)d_in[6];
  const float* bv    = (const float*)d_in[7];
  const float* Wo    = (const float*)d_in[8];
  const float* bo    = (const float*)d_in[9];
  float* out = (float*)d_out;
  char* ws = (char*)d_ws;

  // layout (36.5 MB core); Xb reused as Ob
  bf16_t* Xb  = (bf16_t*)(ws);                 //  5,767,168 B
  bf16_t* Wt  = (bf16_t*)(ws + 5767168);       // 11,894,784 B (Wq^T|Wk^T|Wv^T)
  bf16_t* Qh  = (bf16_t*)(ws + 17661952);      //  6,291,456 B  [16][2048][96]
  bf16_t* Kh  = (bf16_t*)(ws + 23953408);      //  6,291,456 B  [16][2048][96]
  bf16_t* Vt  = (bf16_t*)(ws + 30244864);      //  6,291,456 B  [16][96][2048]
  bf16_t* Ob  = Xb;
  const size_t NEED_ALL = 36536320ull + 3964928ull;   // + separate Wo^T
  const bool sep_wot = (ws_size >= NEED_ALL);
  bf16_t* Wot = sep_wot ? (bf16_t*)(ws + 36536320) : Wt;

  // zero Q (pad cols 88..95 must be 0; K pads then contribute 0*garbage)
  hipMemsetAsync(Qh, 0, 6291456, stream);

  k_convert_x<<<(T_PAD * DM / 4 + 255) / 256, 256, 0, stream>>>(x, Xb);
  if (sep_wot) {
    k_transpose4<<<4 * 484, 256, 0, stream>>>(Wq, Wk, Wv, Wo, Wt, Wot);
  } else {
    k_transpose4<<<3 * 484, 256, 0, stream>>>(Wq, Wk, Wv, Wo, Wt, Wot);
  }

  k_gemm_qkv<<<16 * 33, 256, 0, stream>>>(Xb, Wt, bq, bk, bv, freqs, Qh, Kh, Vt);

  if (!sep_wot)   // Wqkv^T dead after k_gemm_qkv; reuse its space
    k_transpose4<<<484, 256, 0, stream>>>(Wo, Wo, Wo, Wo, Wot, Wot);

  k_attn<<<NHEAD * 32, 256, 0, stream>>>(Qh, Kh, Vt, Ob);
  k_gemm_out64<<<32 * 11, 256, 0, stream>>>(Ob, Wot, bo, out);
}

// Round 5
// 277.872 us; speedup vs baseline: 1.0892x; 1.0892x over previous
//
#include <hip/hip_runtime.h>
#include <hip/hip_bf16.h>
#include <stdint.h>
#include <stddef.h>

typedef __bf16 bf16_t;
typedef __bf16 bf16x8 __attribute__((ext_vector_type(8)));
typedef __bf16 bf16x4 __attribute__((ext_vector_type(4)));
typedef __bf16 bf16x2 __attribute__((ext_vector_type(2)));
typedef float  f32x4  __attribute__((ext_vector_type(4)));

#define T_SEQ 2032
#define T_PAD 2048
#define DM    1408
#define NHEAD 16
#define HD    88
#define HP    96
#define VST   2112   // V row stride (33*128B -> channel-spread)
#define KVB   64
#define NT    (T_PAD / KVB)
#define SM_SCALE 0.10660035817780521f   // 88^-0.5
#define LOG2E 1.4426950408889634f
#define DEFER_THR 8.0f

// -------- async global->LDS (16B per lane, wave-uniform LDS base) --------
__device__ __forceinline__ void gload_lds16(const bf16_t* g, bf16_t* l) {
  __builtin_amdgcn_global_load_lds(
      (__attribute__((address_space(1))) void*)(g),
      (__attribute__((address_space(3))) void*)(l), 16, 0, 0);
}

// ---------------- convert x (f32 [2032][1408]) -> bf16 [2048][1408], pad 0
__global__ void k_convert_x(const float* __restrict__ x, bf16_t* __restrict__ Xb) {
  int idx = blockIdx.x * 256 + threadIdx.x;
  const int total = T_PAD * DM / 4;
  if (idx >= total) return;
  int base = idx * 4;
  int t = base / DM;
  float4 v;
  if (t < T_SEQ) v = *(const float4*)(x + base);
  else           v = make_float4(0.f, 0.f, 0.f, 0.f);
  bf16x4 o;
  o[0] = (bf16_t)v.x; o[1] = (bf16_t)v.y; o[2] = (bf16_t)v.z; o[3] = (bf16_t)v.w;
  *(bf16x4*)(Xb + base) = o;
}

// ---------------- transpose+convert, 64x64 tiles, vectorized both sides
__global__ void k_transpose4(const float* __restrict__ W0, const float* __restrict__ W1,
                             const float* __restrict__ W2, const float* __restrict__ W3,
                             bf16_t* __restrict__ d012, bf16_t* __restrict__ d3) {
  const int which = blockIdx.x / 484;
  const int b = blockIdx.x % 484;
  const float* src = (which == 0) ? W0 : (which == 1) ? W1 : (which == 2) ? W2 : W3;
  bf16_t* dst = (which < 3) ? (d012 + (size_t)which * DM * DM) : d3;
  const int tr = b / 22, tc = b % 22;
  __shared__ float tile[64][65];
  const int t = threadIdx.x;
  const int row = t >> 2, l4 = t & 3;
#pragma unroll
  for (int i = 0; i < 4; ++i) {
    float4 v = *(const float4*)(src + (size_t)(tr * 64 + row) * DM + tc * 64 + l4 * 16 + i * 4);
    *(float4*)&tile[row][l4 * 16 + i * 4] = v;
  }
  __syncthreads();
  const int jj = t >> 2;
#pragma unroll
  for (int it = 0; it < 2; ++it) {
    const int c = (t & 3) + 4 * it;
    bf16x8 o;
#pragma unroll
    for (int e = 0; e < 8; ++e) o[e] = (bf16_t)tile[c * 8 + e][jj];
    *(bf16x8*)(dst + (size_t)(tc * 64 + jj) * DM + tr * 64 + c * 8) = o;
  }
}

// ---------------- shared GEMM mainloop: 128x128 tile, BK=32, double-buffered
__device__ __forceinline__ void gemm_main_1408(
    const bf16_t* __restrict__ A, const bf16_t* __restrict__ Bt,
    bf16_t* As, bf16_t* Bs, int m0, int n0, f32x4 acc[4][4]) {
  const int tid = threadIdx.x;
  const int w = tid >> 6, lane = tid & 63;
  const int l15 = lane & 15, lg = lane >> 4;
  const int b0 = w * 2048 + lane * 16;
  const int r0 = b0 >> 6, k0 = (b0 & 63) >> 1;
  const int b1 = b0 + 1024;
  const int r1 = b1 >> 6, k1 = (b1 & 63) >> 1;
  const int wr = w >> 1, wc = w & 1;
  const size_t aoff0 = (size_t)(m0 + r0) * DM + k0;
  const size_t aoff1 = (size_t)(m0 + r1) * DM + k1;
  const size_t boff0 = (size_t)(n0 + r0) * DM + k0;
  const size_t boff1 = (size_t)(n0 + r1) * DM + k1;
  gload_lds16(A + aoff0, As + w * 1024);
  gload_lds16(A + aoff1, As + w * 1024 + 512);
  gload_lds16(Bt + boff0, Bs + w * 1024);
  gload_lds16(Bt + boff1, Bs + w * 1024 + 512);
  for (int kt = 0; kt < 44; ++kt) {
    const int cur = kt & 1;
    const int kon = ((kt < 43) ? kt + 1 : 43) * 32;
    const int db = (cur ^ 1) * 4096;
    gload_lds16(A + aoff0 + kon, As + db + w * 1024);
    gload_lds16(A + aoff1 + kon, As + db + w * 1024 + 512);
    gload_lds16(Bt + boff0 + kon, Bs + db + w * 1024);
    gload_lds16(Bt + boff1 + kon, Bs + db + w * 1024 + 512);
    asm volatile("s_waitcnt vmcnt(4)" ::: "memory");
    __builtin_amdgcn_s_barrier();
    const bf16_t* Ac = As + cur * 4096;
    const bf16_t* Bc = Bs + cur * 4096;
    bf16x8 av[4], bv[4];
#pragma unroll
    for (int m = 0; m < 4; ++m)
      av[m] = *(const bf16x8*)(Ac + (wr * 64 + m * 16 + l15) * 32 + lg * 8);
#pragma unroll
    for (int n = 0; n < 4; ++n)
      bv[n] = *(const bf16x8*)(Bc + (wc * 64 + n * 16 + l15) * 32 + lg * 8);
    __builtin_amdgcn_s_setprio(1);
#pragma unroll
    for (int m = 0; m < 4; ++m)
#pragma unroll
      for (int n = 0; n < 4; ++n)
        acc[m][n] = __builtin_amdgcn_mfma_f32_16x16x32_bf16(av[m], bv[n], acc[m][n], 0, 0, 0);
    __builtin_amdgcn_s_setprio(0);
    __builtin_amdgcn_s_barrier();
  }
  asm volatile("s_waitcnt vmcnt(0)" ::: "memory");
}

// ---------------- GEMM 1: X @ Wqkv^T -> Q/K/V scatter, fused RoPE + bias
__global__ __launch_bounds__(256, 3) void k_gemm_qkv(
    const bf16_t* __restrict__ A, const bf16_t* __restrict__ Bt,
    const float* __restrict__ bq, const float* __restrict__ bk,
    const float* __restrict__ bvp, const float* __restrict__ freqs,
    bf16_t* __restrict__ Qh, bf16_t* __restrict__ Kh, bf16_t* __restrict__ Vt) {
  __shared__ bf16_t As[2 * 4096];
  __shared__ bf16_t Bs[2 * 4096];
  const int bid = blockIdx.x;
  const int sbid = (bid & 7) * 66 + (bid >> 3);   // 528 = 66*8
  const int mt = sbid / 33, nt = sbid % 33;
  f32x4 acc[4][4];
#pragma unroll
  for (int m = 0; m < 4; ++m)
#pragma unroll
    for (int n = 0; n < 4; ++n) acc[m][n] = (f32x4){0.f, 0.f, 0.f, 0.f};
  gemm_main_1408(A, Bt, As, Bs, mt * 128, nt * 128, acc);
  const int tid = threadIdx.x, w = tid >> 6, lane = tid & 63;
  const int l15 = lane & 15, lg = lane >> 4;
  const int wr = w >> 1, wc = w & 1;
  const int cb = nt * 128 + wc * 64, rb = mt * 128 + wr * 64;
#pragma unroll
  for (int n = 0; n < 4; ++n) {
    const int col = cb + n * 16 + l15;
    const int seg = (col >= 2 * DM) ? 2 : ((col >= DM) ? 1 : 0);
    const int cc = col - seg * DM;
    const float* bp = (seg == 0) ? bq : (seg == 1) ? bk : bvp;
    const float bval = bp[cc];
    const int hn = cc / 88;
    const int hh = cc - hn * 88;
    const int hbase = hh & ~1;
    const bool odd = hh & 1;
#pragma unroll
    for (int m = 0; m < 4; ++m) {
      const int tb = rb + m * 16 + lg * 4;
      if (seg == 2) {
        bf16x4 vv;
#pragma unroll
        for (int r = 0; r < 4; ++r) vv[r] = (bf16_t)(acc[m][n][r] + bval);
        *(bf16x4*)(Vt + ((size_t)hn * HP + hh) * VST + tb) = vv;
      } else {
#pragma unroll
        for (int r = 0; r < 4; ++r) {
          const int t = tb + r;
          const float v = acc[m][n][r] + bval;
          const float p = __shfl_xor(v, 1);     // partner column (hh^1)
          const int tc2 = (t < T_SEQ) ? t : 0;
          const float c = freqs[tc2 * 88 + hbase];
          const float s = freqs[tc2 * 88 + hbase + 1];
          const float x1 = odd ? p : v;
          const float x2 = odd ? v : p;
          const float ro = odd ? (x1 * s + x2 * c) : (x1 * c - x2 * s);
          if (seg == 0)
            Qh[((size_t)hn * T_PAD + t) * HP + hh] = (bf16_t)(ro * (SM_SCALE * LOG2E));
          else
            Kh[((size_t)hn * T_PAD + t) * HP + hh] = (bf16_t)ro;
        }
      }
    }
  }
}

// ---------------- GEMM 2: attnout @ Wo^T + bo -> f32 out, 64x64 tiles, dbuf
__global__ __launch_bounds__(256, 3) void k_gemm_out64(
    const bf16_t* __restrict__ A, const bf16_t* __restrict__ Bt,
    const float* __restrict__ bo, float* __restrict__ out) {
  __shared__ bf16_t Sm[2 * 4096];   // per buf: A[64][32]@0, B[64][32]@2048
  const int bid = blockIdx.x;
  const int sbid = (bid & 7) * 88 + (bid >> 3);   // 704 = 88*8
  const int mt = sbid / 22, nt = sbid % 22;
  const int m0 = mt * 64, n0 = nt * 64;
  const int tid = threadIdx.x, w = tid >> 6, lane = tid & 63;
  const int l15 = lane & 15, lg = lane >> 4;
  const int wr = w >> 1, wc = w & 1;
  const bf16_t* srcp[2];
  size_t srco[2];
  int dste[2];
#pragma unroll
  for (int p = 0; p < 2; ++p) {
    const int off = (w * 2 + p) * 1024;
    const int o = off + lane * 16;
    dste[p] = off >> 1;
    if (off < 4096) {
      int r = o >> 6, k = (o & 63) >> 1;
      srcp[p] = A; srco[p] = (size_t)(m0 + r) * DM + k;
    } else {
      int ob = o - 4096;
      int r = ob >> 6, k = (ob & 63) >> 1;
      srcp[p] = Bt; srco[p] = (size_t)(n0 + r) * DM + k;
    }
  }
  f32x4 acc[2][2];
#pragma unroll
  for (int m = 0; m < 2; ++m)
#pragma unroll
    for (int n = 0; n < 2; ++n) acc[m][n] = (f32x4){0.f, 0.f, 0.f, 0.f};
#pragma unroll
  for (int p = 0; p < 2; ++p) gload_lds16(srcp[p] + srco[p], Sm + dste[p]);
  for (int kt = 0; kt < 44; ++kt) {
    const int cur = kt & 1;
    const int kon = ((kt < 43) ? kt + 1 : 43) * 32;
    const int db = (cur ^ 1) * 4096;
#pragma unroll
    for (int p = 0; p < 2; ++p)
      gload_lds16(srcp[p] + srco[p] + kon, Sm + db + dste[p]);
    asm volatile("s_waitcnt vmcnt(2)" ::: "memory");
    __builtin_amdgcn_s_barrier();
    const bf16_t* Sc = Sm + cur * 4096;
    bf16x8 av[2], bv2[2];
#pragma unroll
    for (int m = 0; m < 2; ++m)
      av[m] = *(const bf16x8*)(Sc + (wr * 32 + m * 16 + l15) * 32 + lg * 8);
#pragma unroll
    for (int n = 0; n < 2; ++n)
      bv2[n] = *(const bf16x8*)(Sc + 2048 + (wc * 32 + n * 16 + l15) * 32 + lg * 8);
    __builtin_amdgcn_s_setprio(1);
#pragma unroll
    for (int m = 0; m < 2; ++m)
#pragma unroll
      for (int n = 0; n < 2; ++n)
        acc[m][n] = __builtin_amdgcn_mfma_f32_16x16x32_bf16(av[m], bv2[n], acc[m][n], 0, 0, 0);
    __builtin_amdgcn_s_setprio(0);
    __builtin_amdgcn_s_barrier();
  }
  asm volatile("s_waitcnt vmcnt(0)" ::: "memory");
#pragma unroll
  for (int n = 0; n < 2; ++n) {
    const int col = n0 + wc * 32 + n * 16 + l15;
    const float bval = bo[col];
#pragma unroll
    for (int m = 0; m < 2; ++m) {
#pragma unroll
      for (int r = 0; r < 4; ++r) {
        const int t = m0 + wr * 32 + m * 16 + lg * 4 + r;
        if (t < T_SEQ) out[(size_t)t * DM + col] = acc[m][n][r] + bval;
      }
    }
  }
}

// ---------------- flash attention: staged-K (dbuf) + direct-reg V
// 1 WG = (head, 64 q rows), 4 waves x 16 rows, KVB=64, swapped QK^T,
// exp2 domain, defer-max, packed P bounce via per-wave LDS.
__global__ __launch_bounds__(256, 2) void k_attn(
    const bf16_t* __restrict__ Qh, const bf16_t* __restrict__ Kh,
    const bf16_t* __restrict__ Vt, bf16_t* __restrict__ Ob) {
  __shared__ bf16_t Ks[2][KVB * 128];   // 2 x 16KB, 256B rows, XOR swizzled
  __shared__ bf16_t Ps[4][16 * 72];     // per-wave P[q][k], 2.25KB each
  const int tid = threadIdx.x;
  const int w = tid >> 6, lane = tid & 63;
  const int l15 = lane & 15, lg = lane >> 4;
  const int swz = l15 & 7;
  const int bid = blockIdx.x;
  const int sbid = (bid & 7) * 64 + (bid >> 3);   // 512 = 64*8
  const int head = sbid >> 5;
  const int qt = sbid & 31;
  const bf16_t* Qn = Qh + (size_t)head * T_PAD * HP;
  const bf16_t* Kn = Kh + (size_t)head * T_PAD * HP;
  const bf16_t* Vn = Vt + (size_t)head * HP * VST;
  const int q0 = qt * 64 + w * 16;

  bf16x8 qf[3];
#pragma unroll
  for (int kh = 0; kh < 3; ++kh)
    qf[kh] = *(const bf16x8*)(Qn + (size_t)(q0 + l15) * HP + kh * 32 + lg * 8);

  f32x4 oacc[6];
#pragma unroll
  for (int j = 0; j < 6; ++j) oacc[j] = (f32x4){0.f, 0.f, 0.f, 0.f};
  float mrow = -1e30f;   // per-lane, q = l15 (log2 domain)
  float lrowp = 0.f;

  // K staging addresses: LDS tile [64][128] linear; global stride HP=96,
  // source pre-swizzled (chunks >=12 read row-overrun garbage, never consumed)
  int kro[4], kco[4];
#pragma unroll
  for (int p = 0; p < 4; ++p) {
    int o = (w * 4 + p) * 1024 + lane * 16;
    int row = o >> 8, ch = (o >> 4) & 15;
    kro[p] = row; kco[p] = (ch ^ (row & 7)) << 3;
  }
  // prologue: K(0) -> Ks[0]
#pragma unroll
  for (int p = 0; p < 4; ++p)
    gload_lds16(Kn + (size_t)kro[p] * HP + kco[p], &Ks[0][(w * 4 + p) * 512]);

  for (int kvt = 0; kvt < NT; ++kvt) {
    const int s0 = kvt * KVB;
    const int cur = kvt & 1;
    const int nxt = (kvt < NT - 1) ? kvt + 1 : kvt;
#pragma unroll
    for (int p = 0; p < 4; ++p)
      gload_lds16(Kn + (size_t)(nxt * KVB + kro[p]) * HP + kco[p],
                  &Ks[cur ^ 1][(w * 4 + p) * 512]);
    asm volatile("s_waitcnt vmcnt(4)" ::: "memory");
    __builtin_amdgcn_s_barrier();

    const bf16_t* Kc = Ks[cur];
    // S^T = K @ Q^T (64 x 16): lane holds 16 scores for q = l15
    f32x4 sf[4];
    __builtin_amdgcn_s_setprio(1);
#pragma unroll
    for (int ss = 0; ss < 4; ++ss) {
      f32x4 s = {0.f, 0.f, 0.f, 0.f};
#pragma unroll
      for (int kh = 0; kh < 3; ++kh) {
        bf16x8 kf = *(const bf16x8*)(Kc + (ss * 16 + l15) * 128 + (((kh * 4 + lg) ^ swz) << 3));
        s = __builtin_amdgcn_mfma_f32_16x16x32_bf16(kf, qf[kh], s, 0, 0, 0);
      }
      sf[ss] = s;
    }
    __builtin_amdgcn_s_setprio(0);
    // V prefetch direct to regs (latency hides under softmax)
    bf16x8 vf[12];
#pragma unroll
    for (int ks = 0; ks < 2; ++ks)
#pragma unroll
      for (int j = 0; j < 6; ++j)
        vf[ks * 6 + j] = *(const bf16x8*)(
            Vn + (size_t)(j * 16 + l15) * VST + s0 + ks * 32 + lg * 8);
    // mask k >= T_SEQ (last tile only)
    if (s0 + KVB > T_SEQ) {
#pragma unroll
      for (int ss = 0; ss < 4; ++ss)
#pragma unroll
        for (int r = 0; r < 4; ++r)
          if (s0 + ss * 16 + lg * 4 + r >= T_SEQ) sf[ss][r] = -1e30f;
    }
    // row max: 15 in-reg + 2 shfl (reduce over lg groups)
    float tm = sf[0][0];
#pragma unroll
    for (int ss = 0; ss < 4; ++ss)
#pragma unroll
      for (int r = 0; r < 4; ++r) tm = fmaxf(tm, sf[ss][r]);
    tm = fmaxf(tm, __shfl_xor(tm, 16));
    tm = fmaxf(tm, __shfl_xor(tm, 32));
    // defer-max: rescale only on significant growth (wave-uniform branch)
    if (!__all(tm <= mrow + DEFER_THR)) {
      const float mn = fmaxf(mrow, tm);
      const float scv = __builtin_amdgcn_exp2f(mrow - mn);
      mrow = mn;
      lrowp *= scv;
#pragma unroll
      for (int r = 0; r < 4; ++r) {
        const float sq = __shfl(scv, lg * 4 + r, 16);
#pragma unroll
        for (int j = 0; j < 6; ++j) oacc[j][r] *= sq;
      }
    }
    // P = exp2(S - m): packed u32 stores to per-wave LDS
    float rs = 0.f;
#pragma unroll
    for (int ss = 0; ss < 4; ++ss)
#pragma unroll
      for (int jj = 0; jj < 2; ++jj) {
        const float p0 = __builtin_amdgcn_exp2f(sf[ss][2 * jj] - mrow);
        const float p1 = __builtin_amdgcn_exp2f(sf[ss][2 * jj + 1] - mrow);
        rs += p0 + p1;
        bf16x2 pk; pk[0] = (bf16_t)p0; pk[1] = (bf16_t)p1;
        *(bf16x2*)(&Ps[w][l15 * 72 + ss * 16 + lg * 4 + 2 * jj]) = pk;
      }
    lrowp += rs;
    // O += P @ V
    __builtin_amdgcn_s_setprio(1);
#pragma unroll
    for (int ks = 0; ks < 2; ++ks) {
      bf16x8 pa = *(const bf16x8*)(&Ps[w][l15 * 72 + ks * 32 + lg * 8]);
#pragma unroll
      for (int j = 0; j < 6; ++j)
        oacc[j] = __builtin_amdgcn_mfma_f32_16x16x32_bf16(pa, vf[ks * 6 + j], oacc[j], 0, 0, 0);
    }
    __builtin_amdgcn_s_setprio(0);
    __builtin_amdgcn_s_barrier();
  }
  asm volatile("s_waitcnt vmcnt(0)" ::: "memory");

  // finish row-sum reduce; fetch per-output-row sums
  lrowp += __shfl_xor(lrowp, 16);
  lrowp += __shfl_xor(lrowp, 32);
  float lq[4];
#pragma unroll
  for (int r = 0; r < 4; ++r) lq[r] = __shfl(lrowp, lg * 4 + r, 16);
  // write attention output, [t][n*88+h] bf16 (oacc: h = j*16+l15, q = lg*4+r)
#pragma unroll
  for (int j = 0; j < 6; ++j) {
    const int h = j * 16 + l15;
    if (h < HD) {
#pragma unroll
      for (int r = 0; r < 4; ++r) {
        const int t = q0 + lg * 4 + r;
        if (t < T_SEQ)
          Ob[(size_t)t * DM + head * HD + h] = (bf16_t)(oacc[j][r] / lq[r]);
      }
    }
  }
}

// ---------------- host side ----------------
extern "C" void kernel_launch(void* const* d_in, const int* in_sizes, int n_in,
                              void* d_out, int out_size, void* d_ws, size_t ws_size,
                              hipStream_t stream) {
  (void)in_sizes; (void)n_in; (void)out_size;
  const float* x     = (const float*)d_in[0];
  const float* freqs = (const float*)d_in[1];
  const float* Wq    = (const float*)d_in[2];
  const float* bq    = (const float*)d_in[3];
  const float* Wk    = (const float*)d_in[4];
  const float* bk    = (const float*)d_in[5];
  const float* Wv    = (const float*)d_in[6];
  const float* bv    = (const float*)d_in[7];
  const float* Wo    = (const float*)d_in[8];
  const float* bo    = (const float*)d_in[9];
  float* out = (float*)d_out;
  char* ws = (char*)d_ws;

  // layout (36.73 MB core); Xb reused as Ob
  bf16_t* Xb  = (bf16_t*)(ws);                 //  5,767,168 B
  bf16_t* Wt  = (bf16_t*)(ws + 5767168);       // 11,894,784 B (Wq^T|Wk^T|Wv^T)
  bf16_t* Qh  = (bf16_t*)(ws + 17661952);      //  6,291,456 B  [16][2048][96]
  bf16_t* Kh  = (bf16_t*)(ws + 23953408);      //  6,291,456 B  [16][2048][96]
  bf16_t* Vt  = (bf16_t*)(ws + 30244864);      //  6,488,064 B  [16][96][2112]
  bf16_t* Ob  = Xb;
  const size_t NEED_ALL = 36732928ull + 3964928ull;
  const bool sep_wot = (ws_size >= NEED_ALL);
  bf16_t* Wot = sep_wot ? (bf16_t*)(ws + 36732928) : Wt;

  // zero Q only (pad cols 88..95 must be 0 so K/V pad garbage is annihilated)
  hipMemsetAsync(Qh, 0, 6291456, stream);

  k_convert_x<<<(T_PAD * DM / 4 + 255) / 256, 256, 0, stream>>>(x, Xb);
  if (sep_wot) {
    k_transpose4<<<4 * 484, 256, 0, stream>>>(Wq, Wk, Wv, Wo, Wt, Wot);
  } else {
    k_transpose4<<<3 * 484, 256, 0, stream>>>(Wq, Wk, Wv, Wo, Wt, Wot);
  }

  k_gemm_qkv<<<16 * 33, 256, 0, stream>>>(Xb, Wt, bq, bk, bv, freqs, Qh, Kh, Vt);

  if (!sep_wot)
    k_transpose4<<<484, 256, 0, stream>>>(Wo, Wo, Wo, Wo, Wot, Wot);

  k_attn<<<NHEAD * 32, 256, 0, stream>>>(Qh, Kh, Vt, Ob);
  k_gemm_out64<<<32 * 22, 256, 0, stream>>>(Ob, Wot, bo, out);
}

// Round 7
// 255.726 us; speedup vs baseline: 1.1835x; 1.0866x over previous
//
#include <hip/hip_runtime.h>
#include <hip/hip_bf16.h>
#include <stdint.h>
#include <stddef.h>

typedef __bf16 bf16_t;
typedef __bf16 bf16x8 __attribute__((ext_vector_type(8)));
typedef __bf16 bf16x4 __attribute__((ext_vector_type(4)));
typedef __bf16 bf16x2 __attribute__((ext_vector_type(2)));
typedef float  f32x4  __attribute__((ext_vector_type(4)));

#define T_SEQ 2032
#define T_PAD 2048
#define DM    1408
#define NHEAD 16
#define HD    88
#define HP    96
#define VST   2112   // V row stride (spreads channels)
#define SM_SCALE 0.10660035817780521f   // 88^-0.5
#define LOG2E 1.4426950408889634f
#define DEFER_THR 8.0f

// -------- async global->LDS (16B per lane, wave-uniform LDS base) --------
__device__ __forceinline__ void gload_lds16(const bf16_t* g, bf16_t* l) {
  __builtin_amdgcn_global_load_lds(
      (__attribute__((address_space(1))) void*)(g),
      (__attribute__((address_space(3))) void*)(l), 16, 0, 0);
}

// ---------------- convert x (f32 [2032][1408]) -> bf16 [2048][1408], pad 0
__global__ void k_convert_x(const float* __restrict__ x, bf16_t* __restrict__ Xb) {
  int idx = blockIdx.x * 256 + threadIdx.x;
  const int total = T_PAD * DM / 4;
  if (idx >= total) return;
  int base = idx * 4;
  int t = base / DM;
  float4 v;
  if (t < T_SEQ) v = *(const float4*)(x + base);
  else           v = make_float4(0.f, 0.f, 0.f, 0.f);
  bf16x4 o;
  o[0] = (bf16_t)v.x; o[1] = (bf16_t)v.y; o[2] = (bf16_t)v.z; o[3] = (bf16_t)v.w;
  *(bf16x4*)(Xb + base) = o;
}

// ---------------- transpose+convert, 64x64 tiles, vectorized both sides
__global__ void k_transpose4(const float* __restrict__ W0, const float* __restrict__ W1,
                             const float* __restrict__ W2, const float* __restrict__ W3,
                             bf16_t* __restrict__ d012, bf16_t* __restrict__ d3) {
  const int which = blockIdx.x / 484;
  const int b = blockIdx.x % 484;
  const float* src = (which == 0) ? W0 : (which == 1) ? W1 : (which == 2) ? W2 : W3;
  bf16_t* dst = (which < 3) ? (d012 + (size_t)which * DM * DM) : d3;
  const int tr = b / 22, tc = b % 22;
  __shared__ float tile[64][65];
  const int t = threadIdx.x;
  const int row = t >> 2, l4 = t & 3;
#pragma unroll
  for (int i = 0; i < 4; ++i) {
    float4 v = *(const float4*)(src + (size_t)(tr * 64 + row) * DM + tc * 64 + l4 * 16 + i * 4);
    *(float4*)&tile[row][l4 * 16 + i * 4] = v;
  }
  __syncthreads();
  const int jj = t >> 2;
#pragma unroll
  for (int it = 0; it < 2; ++it) {
    const int c = (t & 3) + 4 * it;
    bf16x8 o;
#pragma unroll
    for (int e = 0; e < 8; ++e) o[e] = (bf16_t)tile[c * 8 + e][jj];
    *(bf16x8*)(dst + (size_t)(tc * 64 + jj) * DM + tr * 64 + c * 8) = o;
  }
}

// ---------------- shared GEMM mainloop: 128x128 tile, BK=32, double-buffered
__device__ __forceinline__ void gemm_main_1408(
    const bf16_t* __restrict__ A, const bf16_t* __restrict__ Bt,
    bf16_t* As, bf16_t* Bs, int m0, int n0, f32x4 acc[4][4]) {
  const int tid = threadIdx.x;
  const int w = tid >> 6, lane = tid & 63;
  const int l15 = lane & 15, lg = lane >> 4;
  const int b0 = w * 2048 + lane * 16;
  const int r0 = b0 >> 6, k0 = (b0 & 63) >> 1;
  const int b1 = b0 + 1024;
  const int r1 = b1 >> 6, k1 = (b1 & 63) >> 1;
  const int wr = w >> 1, wc = w & 1;
  const size_t aoff0 = (size_t)(m0 + r0) * DM + k0;
  const size_t aoff1 = (size_t)(m0 + r1) * DM + k1;
  const size_t boff0 = (size_t)(n0 + r0) * DM + k0;
  const size_t boff1 = (size_t)(n0 + r1) * DM + k1;
  gload_lds16(A + aoff0, As + w * 1024);
  gload_lds16(A + aoff1, As + w * 1024 + 512);
  gload_lds16(Bt + boff0, Bs + w * 1024);
  gload_lds16(Bt + boff1, Bs + w * 1024 + 512);
  for (int kt = 0; kt < 44; ++kt) {
    const int cur = kt & 1;
    const int kon = ((kt < 43) ? kt + 1 : 43) * 32;
    const int db = (cur ^ 1) * 4096;
    gload_lds16(A + aoff0 + kon, As + db + w * 1024);
    gload_lds16(A + aoff1 + kon, As + db + w * 1024 + 512);
    gload_lds16(Bt + boff0 + kon, Bs + db + w * 1024);
    gload_lds16(Bt + boff1 + kon, Bs + db + w * 1024 + 512);
    asm volatile("s_waitcnt vmcnt(4)" ::: "memory");
    __builtin_amdgcn_s_barrier();
    const bf16_t* Ac = As + cur * 4096;
    const bf16_t* Bc = Bs + cur * 4096;
    bf16x8 av[4], bv[4];
#pragma unroll
    for (int m = 0; m < 4; ++m)
      av[m] = *(const bf16x8*)(Ac + (wr * 64 + m * 16 + l15) * 32 + lg * 8);
#pragma unroll
    for (int n = 0; n < 4; ++n)
      bv[n] = *(const bf16x8*)(Bc + (wc * 64 + n * 16 + l15) * 32 + lg * 8);
    __builtin_amdgcn_s_setprio(1);
#pragma unroll
    for (int m = 0; m < 4; ++m)
#pragma unroll
      for (int n = 0; n < 4; ++n)
        acc[m][n] = __builtin_amdgcn_mfma_f32_16x16x32_bf16(av[m], bv[n], acc[m][n], 0, 0, 0);
    __builtin_amdgcn_s_setprio(0);
    __builtin_amdgcn_s_barrier();
  }
  asm volatile("s_waitcnt vmcnt(0)" ::: "memory");
}

// ---------------- GEMM 1: X @ Wqkv^T -> Q/K/V scatter, fused RoPE + bias
__global__ __launch_bounds__(256, 3) void k_gemm_qkv(
    const bf16_t* __restrict__ A, const bf16_t* __restrict__ Bt,
    const float* __restrict__ bq, const float* __restrict__ bk,
    const float* __restrict__ bvp, const float* __restrict__ freqs,
    bf16_t* __restrict__ Qh, bf16_t* __restrict__ Kh, bf16_t* __restrict__ Vt) {
  __shared__ bf16_t As[2 * 4096];
  __shared__ bf16_t Bs[2 * 4096];
  const int bid = blockIdx.x;
  const int sbid = (bid & 7) * 66 + (bid >> 3);   // 528 = 66*8
  const int mt = sbid / 33, nt = sbid % 33;
  f32x4 acc[4][4];
#pragma unroll
  for (int m = 0; m < 4; ++m)
#pragma unroll
    for (int n = 0; n < 4; ++n) acc[m][n] = (f32x4){0.f, 0.f, 0.f, 0.f};
  gemm_main_1408(A, Bt, As, Bs, mt * 128, nt * 128, acc);
  const int tid = threadIdx.x, w = tid >> 6, lane = tid & 63;
  const int l15 = lane & 15, lg = lane >> 4;
  const int wr = w >> 1, wc = w & 1;
  const int cb = nt * 128 + wc * 64, rb = mt * 128 + wr * 64;
#pragma unroll
  for (int n = 0; n < 4; ++n) {
    const int col = cb + n * 16 + l15;
    const int seg = (col >= 2 * DM) ? 2 : ((col >= DM) ? 1 : 0);
    const int cc = col - seg * DM;
    const float* bp = (seg == 0) ? bq : (seg == 1) ? bk : bvp;
    const float bval = bp[cc];
    const int hn = cc / 88;
    const int hh = cc - hn * 88;
    const int hbase = hh & ~1;
    const bool odd = hh & 1;
#pragma unroll
    for (int m = 0; m < 4; ++m) {
      const int tb = rb + m * 16 + lg * 4;
      if (seg == 2) {
        bf16x4 vv;
#pragma unroll
        for (int r = 0; r < 4; ++r) vv[r] = (bf16_t)(acc[m][n][r] + bval);
        *(bf16x4*)(Vt + ((size_t)hn * HP + hh) * VST + tb) = vv;
      } else {
#pragma unroll
        for (int r = 0; r < 4; ++r) {
          const int t = tb + r;
          const float v = acc[m][n][r] + bval;
          const float p = __shfl_xor(v, 1);     // partner column (hh^1)
          const int tc2 = (t < T_SEQ) ? t : 0;
          const float c = freqs[tc2 * 88 + hbase];
          const float s = freqs[tc2 * 88 + hbase + 1];
          const float x1 = odd ? p : v;
          const float x2 = odd ? v : p;
          const float ro = odd ? (x1 * s + x2 * c) : (x1 * c - x2 * s);
          if (seg == 0)
            Qh[((size_t)hn * T_PAD + t) * HP + hh] = (bf16_t)(ro * (SM_SCALE * LOG2E));
          else
            Kh[((size_t)hn * T_PAD + t) * HP + hh] = (bf16_t)ro;
        }
      }
    }
  }
}

// ---------------- GEMM 2: attnout @ Wo^T + bo -> f32 out, 64x64 tiles, dbuf
__global__ __launch_bounds__(256, 3) void k_gemm_out64(
    const bf16_t* __restrict__ A, const bf16_t* __restrict__ Bt,
    const float* __restrict__ bo, float* __restrict__ out) {
  __shared__ bf16_t Sm[2 * 4096];   // per buf: A[64][32]@0, B[64][32]@2048
  const int bid = blockIdx.x;
  const int sbid = (bid & 7) * 88 + (bid >> 3);   // 704 = 88*8
  const int mt = sbid / 22, nt = sbid % 22;
  const int m0 = mt * 64, n0 = nt * 64;
  const int tid = threadIdx.x, w = tid >> 6, lane = tid & 63;
  const int l15 = lane & 15, lg = lane >> 4;
  const int wr = w >> 1, wc = w & 1;
  const bf16_t* srcp[2];
  size_t srco[2];
  int dste[2];
#pragma unroll
  for (int p = 0; p < 2; ++p) {
    const int off = (w * 2 + p) * 1024;
    const int o = off + lane * 16;
    dste[p] = off >> 1;
    if (off < 4096) {
      int r = o >> 6, k = (o & 63) >> 1;
      srcp[p] = A; srco[p] = (size_t)(m0 + r) * DM + k;
    } else {
      int ob = o - 4096;
      int r = ob >> 6, k = (ob & 63) >> 1;
      srcp[p] = Bt; srco[p] = (size_t)(n0 + r) * DM + k;
    }
  }
  f32x4 acc[2][2];
#pragma unroll
  for (int m = 0; m < 2; ++m)
#pragma unroll
    for (int n = 0; n < 2; ++n) acc[m][n] = (f32x4){0.f, 0.f, 0.f, 0.f};
#pragma unroll
  for (int p = 0; p < 2; ++p) gload_lds16(srcp[p] + srco[p], Sm + dste[p]);
  for (int kt = 0; kt < 44; ++kt) {
    const int cur = kt & 1;
    const int kon = ((kt < 43) ? kt + 1 : 43) * 32;
    const int db = (cur ^ 1) * 4096;
#pragma unroll
    for (int p = 0; p < 2; ++p)
      gload_lds16(srcp[p] + srco[p] + kon, Sm + db + dste[p]);
    asm volatile("s_waitcnt vmcnt(2)" ::: "memory");
    __builtin_amdgcn_s_barrier();
    const bf16_t* Sc = Sm + cur * 4096;
    bf16x8 av[2], bv2[2];
#pragma unroll
    for (int m = 0; m < 2; ++m)
      av[m] = *(const bf16x8*)(Sc + (wr * 32 + m * 16 + l15) * 32 + lg * 8);
#pragma unroll
    for (int n = 0; n < 2; ++n)
      bv2[n] = *(const bf16x8*)(Sc + 2048 + (wc * 32 + n * 16 + l15) * 32 + lg * 8);
    __builtin_amdgcn_s_setprio(1);
#pragma unroll
    for (int m = 0; m < 2; ++m)
#pragma unroll
      for (int n = 0; n < 2; ++n)
        acc[m][n] = __builtin_amdgcn_mfma_f32_16x16x32_bf16(av[m], bv2[n], acc[m][n], 0, 0, 0);
    __builtin_amdgcn_s_setprio(0);
    __builtin_amdgcn_s_barrier();
  }
  asm volatile("s_waitcnt vmcnt(0)" ::: "memory");
#pragma unroll
  for (int n = 0; n < 2; ++n) {
    const int col = n0 + wc * 32 + n * 16 + l15;
    const float bval = bo[col];
#pragma unroll
    for (int m = 0; m < 2; ++m) {
#pragma unroll
      for (int r = 0; r < 4; ++r) {
        const int t = m0 + wr * 32 + m * 16 + lg * 4 + r;
        if (t < T_SEQ) out[(size_t)t * DM + col] = acc[m][n][r] + bval;
      }
    }
  }
}

// ---------------- flash attention v7: q32/wave + in-WG KV-split x4
// WG = (head, 32 q-rows); 4 waves = 4 k-quarters of each staged 128-row K tile.
// grid = 16 x 64 = 1024 -> 3 WG/CU (LDS 42KB), 12 waves/CU.
// K LDS-staged (XOR swizzle); V direct-to-reg (issue pinned by sched_barrier,
// counted vmcnt(6)); swapped QK^T; exp2; defer-max.
// 4 per-wave flash states merged lane-aligned via LDS overlay at the end.
__global__ __launch_bounds__(256, 3) void k_attn(
    const bf16_t* __restrict__ Qh, const bf16_t* __restrict__ Kh,
    const bf16_t* __restrict__ Vt, bf16_t* __restrict__ Ob) {
  __shared__ bf16_t Ks[128 * 128];   // 32KB; rows 256B, chunk^(row&7) swizzle
  __shared__ bf16_t Ps[4][2][640];   // 10KB; per (wave,qb): [16 q][40 pad] k32
  const int tid = threadIdx.x;
  const int w = tid >> 6, lane = tid & 63;     // w = k-quarter
  const int l15 = lane & 15, lg = lane >> 4;
  const int swz = l15 & 7;
  const int bid = blockIdx.x;
  const int sbid = (bid & 7) * 128 + (bid >> 3);   // 1024 = 128*8
  const int head = sbid >> 6;
  const int qt = sbid & 63;
  const bf16_t* Qn = Qh + (size_t)head * T_PAD * HP;
  const bf16_t* Kn = Kh + (size_t)head * T_PAD * HP;
  const bf16_t* Vn = Vt + (size_t)head * HP * VST;
  const int q0 = qt * 32;

  // Q fragments held in regs (q = q0 + qb*16 + l15)
  bf16x8 qf[2][3];
#pragma unroll
  for (int qb = 0; qb < 2; ++qb)
#pragma unroll
    for (int kh = 0; kh < 3; ++kh)
      qf[qb][kh] = *(const bf16x8*)(Qn + (size_t)(q0 + qb * 16 + l15) * HP + kh * 32 + lg * 8);

  f32x4 oacc[2][6];
#pragma unroll
  for (int qb = 0; qb < 2; ++qb)
#pragma unroll
    for (int j = 0; j < 6; ++j) oacc[qb][j] = (f32x4){0.f, 0.f, 0.f, 0.f};
  float m[2] = {-1e30f, -1e30f};
  float l[2] = {0.f, 0.f};

  // K staging: 32 chunks of 1024B, 8 per wave; pre-swizzled global source
  int ksrc[8];
#pragma unroll
  for (int p = 0; p < 8; ++p) {
    int o = (w * 8 + p) * 1024 + lane * 16;
    int row = o >> 8, ch = (o >> 4) & 15;
    ksrc[p] = row * HP + ((ch ^ (row & 7)) << 3);
  }

  for (int t = 0; t < 16; ++t) {
    const int s0 = t * 128;
    // stage K tile (8 chunks/wave)
#pragma unroll
    for (int p = 0; p < 8; ++p)
      gload_lds16(Kn + (size_t)s0 * HP + ksrc[p], Ks + (w * 8 + p) * 512);
    __builtin_amdgcn_sched_barrier(0);   // pin: stages issue before vf loads
    // V reg-loads (stay in flight across the barrier)
    bf16x8 vf[6];
#pragma unroll
    for (int j = 0; j < 6; ++j)
      vf[j] = *(const bf16x8*)(Vn + (size_t)(j * 16 + l15) * VST + s0 + w * 32 + lg * 8);
    __builtin_amdgcn_sched_barrier(0);   // pin: vf loads issued before waitcnt
    asm volatile("s_waitcnt vmcnt(6)" ::: "memory");   // K staged; V in flight
    __builtin_amdgcn_s_barrier();

    // S^T = K @ Q^T over this wave's 32-k quarter
    f32x4 sf[2][2];
#pragma unroll
    for (int qb = 0; qb < 2; ++qb)
#pragma unroll
      for (int ss = 0; ss < 2; ++ss) sf[qb][ss] = (f32x4){0.f, 0.f, 0.f, 0.f};
    __builtin_amdgcn_s_setprio(1);
#pragma unroll
    for (int ss = 0; ss < 2; ++ss)
#pragma unroll
      for (int kh = 0; kh < 3; ++kh) {
        bf16x8 kf = *(const bf16x8*)(
            Ks + (w * 32 + ss * 16 + l15) * 128 + (((kh * 4 + lg) ^ swz) << 3));
        sf[0][ss] = __builtin_amdgcn_mfma_f32_16x16x32_bf16(kf, qf[0][kh], sf[0][ss], 0, 0, 0);
        sf[1][ss] = __builtin_amdgcn_mfma_f32_16x16x32_bf16(kf, qf[1][kh], sf[1][ss], 0, 0, 0);
      }
    __builtin_amdgcn_s_setprio(0);
    // mask k >= T_SEQ (last tile only)
    if (s0 + 128 > T_SEQ) {
#pragma unroll
      for (int ss = 0; ss < 2; ++ss)
#pragma unroll
        for (int r = 0; r < 4; ++r)
          if (s0 + w * 32 + ss * 16 + lg * 4 + r >= T_SEQ) {
            sf[0][ss][r] = -1e30f; sf[1][ss][r] = -1e30f;
          }
    }
    // per-qb row max over this wave's 32 k: in-reg + 2 shfl
    float tm[2];
#pragma unroll
    for (int qb = 0; qb < 2; ++qb) {
      float v = fmaxf(fmaxf(sf[qb][0][0], sf[qb][0][1]), fmaxf(sf[qb][0][2], sf[qb][0][3]));
      v = fmaxf(v, fmaxf(fmaxf(sf[qb][1][0], sf[qb][1][1]), fmaxf(sf[qb][1][2], sf[qb][1][3])));
      v = fmaxf(v, __shfl_xor(v, 16));
      v = fmaxf(v, __shfl_xor(v, 32));
      tm[qb] = v;
    }
    // defer-max
    if (!__all((tm[0] <= m[0] + DEFER_THR) && (tm[1] <= m[1] + DEFER_THR))) {
#pragma unroll
      for (int qb = 0; qb < 2; ++qb) {
        const float mn = fmaxf(m[qb], tm[qb]);
        const float scv = __builtin_amdgcn_exp2f(m[qb] - mn);
        m[qb] = mn;
        l[qb] *= scv;
#pragma unroll
        for (int r = 0; r < 4; ++r) {
          const float sq = __shfl(scv, lg * 4 + r, 16);
#pragma unroll
          for (int j = 0; j < 6; ++j) oacc[qb][j][r] *= sq;
        }
      }
    }
    // P = exp2(S - m) -> per-wave LDS (packed bf16x2)
#pragma unroll
    for (int qb = 0; qb < 2; ++qb) {
      float rs = 0.f;
#pragma unroll
      for (int ss = 0; ss < 2; ++ss)
#pragma unroll
        for (int jj = 0; jj < 2; ++jj) {
          const float p0 = __builtin_amdgcn_exp2f(sf[qb][ss][2 * jj] - m[qb]);
          const float p1 = __builtin_amdgcn_exp2f(sf[qb][ss][2 * jj + 1] - m[qb]);
          rs += p0 + p1;
          bf16x2 pk; pk[0] = (bf16_t)p0; pk[1] = (bf16_t)p1;
          *(bf16x2*)(&Ps[w][qb][l15 * 40 + ss * 16 + lg * 4 + 2 * jj]) = pk;
        }
      l[qb] += rs;
    }
    // O += P @ V (V from regs; only the 6 vf outstanding now)
    asm volatile("s_waitcnt vmcnt(0)" ::: "memory");
    bf16x8 pa0 = *(const bf16x8*)(&Ps[w][0][l15 * 40 + lg * 8]);
    bf16x8 pa1 = *(const bf16x8*)(&Ps[w][1][l15 * 40 + lg * 8]);
    __builtin_amdgcn_s_setprio(1);
#pragma unroll
    for (int j = 0; j < 6; ++j) {
      oacc[0][j] = __builtin_amdgcn_mfma_f32_16x16x32_bf16(pa0, vf[j], oacc[0][j], 0, 0, 0);
      oacc[1][j] = __builtin_amdgcn_mfma_f32_16x16x32_bf16(pa1, vf[j], oacc[1][j], 0, 0, 0);
    }
    __builtin_amdgcn_s_setprio(0);
    __builtin_amdgcn_s_barrier();   // all waves done with Ks -> safe to restage
  }
  asm volatile("s_waitcnt vmcnt(0)" ::: "memory");

  // finish per-wave row sums (reduce over lg; l becomes per-lane, q = l15)
#pragma unroll
  for (int qb = 0; qb < 2; ++qb) {
    l[qb] += __shfl_xor(l[qb], 16);
    l[qb] += __shfl_xor(l[qb], 32);
  }

  // ---- sequential lane-aligned merge of the 4 k-quarter partials.
  // Blob (f32, overlays Ks, 13312 B): O [(qb*6+j)*4+r]*64+lane (3072),
  // m @3072+qb*64+lane, l @3200+qb*64+lane. Same lane = same (q,h) element.
  float* MB = (float*)Ks;
  for (int p = 1; p < 4; ++p) {
    if (w == p) {
#pragma unroll
      for (int qb = 0; qb < 2; ++qb) {
#pragma unroll
        for (int j = 0; j < 6; ++j)
#pragma unroll
          for (int r = 0; r < 4; ++r)
            MB[((qb * 6 + j) * 4 + r) * 64 + lane] = oacc[qb][j][r];
        MB[3072 + qb * 64 + lane] = m[qb];
        MB[3200 + qb * 64 + lane] = l[qb];
      }
    }
    __syncthreads();
    if (w == 0) {
#pragma unroll
      for (int qb = 0; qb < 2; ++qb) {
        const float mp = MB[3072 + qb * 64 + lane];
        const float lp = MB[3200 + qb * 64 + lane];
        const float mn = fmaxf(m[qb], mp);
        const float wa = __builtin_amdgcn_exp2f(m[qb] - mn);
        const float wb = __builtin_amdgcn_exp2f(mp - mn);
        m[qb] = mn;
        l[qb] = l[qb] * wa + lp * wb;
#pragma unroll
        for (int r = 0; r < 4; ++r) {
          const float swa = __shfl(wa, lg * 4 + r, 16);
          const float swb = __shfl(wb, lg * 4 + r, 16);
#pragma unroll
          for (int j = 0; j < 6; ++j)
            oacc[qb][j][r] = oacc[qb][j][r] * swa +
                             MB[((qb * 6 + j) * 4 + r) * 64 + lane] * swb;
        }
      }
    }
    __syncthreads();
  }

  if (w == 0) {
    // normalize and write Ob [t][head*88+h]
#pragma unroll
    for (int qb = 0; qb < 2; ++qb) {
      float lq[4];
#pragma unroll
      for (int r = 0; r < 4; ++r) lq[r] = __shfl(l[qb], lg * 4 + r, 16);
#pragma unroll
      for (int j = 0; j < 6; ++j) {
        const int h = j * 16 + l15;
        if (h < HD) {
#pragma unroll
          for (int r = 0; r < 4; ++r) {
            const int t = q0 + qb * 16 + lg * 4 + r;
            if (t < T_SEQ)
              Ob[(size_t)t * DM + head * HD + h] = (bf16_t)(oacc[qb][j][r] / lq[r]);
          }
        }
      }
    }
  }
}

// ---------------- host side ----------------
extern "C" void kernel_launch(void* const* d_in, const int* in_sizes, int n_in,
                              void* d_out, int out_size, void* d_ws, size_t ws_size,
                              hipStream_t stream) {
  (void)in_sizes; (void)n_in; (void)out_size;
  const float* x     = (const float*)d_in[0];
  const float* freqs = (const float*)d_in[1];
  const float* Wq    = (const float*)d_in[2];
  const float* bq    = (const float*)d_in[3];
  const float* Wk    = (const float*)d_in[4];
  const float* bk    = (const float*)d_in[5];
  const float* Wv    = (const float*)d_in[6];
  const float* bv    = (const float*)d_in[7];
  const float* Wo    = (const float*)d_in[8];
  const float* bo    = (const float*)d_in[9];
  float* out = (float*)d_out;
  char* ws = (char*)d_ws;

  // layout (36.73 MB core); Xb reused as Ob
  bf16_t* Xb  = (bf16_t*)(ws);                 //  5,767,168 B
  bf16_t* Wt  = (bf16_t*)(ws + 5767168);       // 11,894,784 B (Wq^T|Wk^T|Wv^T)
  bf16_t* Qh  = (bf16_t*)(ws + 17661952);      //  6,291,456 B  [16][2048][96]
  bf16_t* Kh  = (bf16_t*)(ws + 23953408);      //  6,291,456 B  [16][2048][96]
  bf16_t* Vt  = (bf16_t*)(ws + 30244864);      //  6,488,064 B  [16][96][2112]
  bf16_t* Ob  = Xb;
  const size_t NEED_ALL = 36732928ull + 3964928ull;
  const bool sep_wot = (ws_size >= NEED_ALL);
  bf16_t* Wot = sep_wot ? (bf16_t*)(ws + 36732928) : Wt;

  // zero Q only (pad cols 88..95 must be 0 so K/V pad garbage is annihilated)
  hipMemsetAsync(Qh, 0, 6291456, stream);

  k_convert_x<<<(T_PAD * DM / 4 + 255) / 256, 256, 0, stream>>>(x, Xb);
  if (sep_wot) {
    k_transpose4<<<4 * 484, 256, 0, stream>>>(Wq, Wk, Wv, Wo, Wt, Wot);
  } else {
    k_transpose4<<<3 * 484, 256, 0, stream>>>(Wq, Wk, Wv, Wo, Wt, Wot);
  }

  k_gemm_qkv<<<16 * 33, 256, 0, stream>>>(Xb, Wt, bq, bk, bv, freqs, Qh, Kh, Vt);

  if (!sep_wot)
    k_transpose4<<<484, 256, 0, stream>>>(Wo, Wo, Wo, Wo, Wot, Wot);

  k_attn<<<16 * 64, 256, 0, stream>>>(Qh, Kh, Vt, Ob);
  k_gemm_out64<<<32 * 22, 256, 0, stream>>>(Ob, Wot, bo, out);
}